// Round 1
// baseline (99.983 us; speedup 1.0000x reference)
//
#include <hip/hip_runtime.h>

// Int4 weight-only embedding: out[tok, :] = (weight[x[tok], :] - zp) * scale
// V=128000, D=1024, G_SIZE=32, NG=32. Output fp32.

#define EMB_D   1024
#define EMB_NG  32

__global__ __launch_bounds__(256) void int4_embed_dq_kernel(
    const int*   __restrict__ x,       // [ntok]
    const int*   __restrict__ weight,  // [V, D] int4 values stored as int32
    const float* __restrict__ scale,   // [V, NG]
    const int*   __restrict__ zp,      // [V, NG]
    float*       __restrict__ out,     // [ntok, D]
    int ntok)
{
    const int tok = blockIdx.x;
    if (tok >= ntok) return;

    const int v  = x[tok];               // uniform across block -> scalar load
    const int t  = threadIdx.x;          // 0..255, each handles 4 elems
    const int d0 = t << 2;               // 0,4,...,1020
    const int g  = d0 >> 5;              // group of 32: 8 consecutive lanes share

    const float s = scale[(size_t)v * EMB_NG + g];
    const float z = (float)zp[(size_t)v * EMB_NG + g];

    const int4 w4 = *reinterpret_cast<const int4*>(
        &weight[(size_t)v * EMB_D + d0]);

    float4 o;
    o.x = ((float)w4.x - z) * s;
    o.y = ((float)w4.y - z) * s;
    o.z = ((float)w4.z - z) * s;
    o.w = ((float)w4.w - z) * s;

    *reinterpret_cast<float4*>(&out[(size_t)tok * EMB_D + d0]) = o;
}

extern "C" void kernel_launch(void* const* d_in, const int* in_sizes, int n_in,
                              void* d_out, int out_size, void* d_ws, size_t ws_size,
                              hipStream_t stream) {
    const int*   x      = (const int*)d_in[0];
    const int*   weight = (const int*)d_in[1];
    const float* scale  = (const float*)d_in[2];
    const int*   zp     = (const int*)d_in[3];
    float*       out    = (float*)d_out;

    const int ntok = in_sizes[0];        // 32 * 2048 = 65536

    dim3 grid(ntok);
    dim3 block(256);
    int4_embed_dq_kernel<<<grid, block, 0, stream>>>(x, weight, scale, zp, out, ntok);
}

// Round 3
// 87.702 us; speedup vs baseline: 1.1400x; 1.1400x over previous
//
#include <hip/hip_runtime.h>

// Int4 weight-only embedding: out[tok, :] = (weight[x[tok], :] - zp) * scale
// V=128000, D=1024, G_SIZE=32, NG=32. Output fp32.
// R3: 4 tokens per block (4-deep MLP per thread) + non-temporal output stores,
//     using clang ext_vector types (HIP float4 is a class the builtin rejects).

#define EMB_D   1024
#define EMB_NG  32
#define TOKS_PER_BLOCK 4

typedef float f32x4 __attribute__((ext_vector_type(4)));
typedef int   i32x4 __attribute__((ext_vector_type(4)));

__global__ __launch_bounds__(256) void int4_embed_dq_kernel(
    const int*   __restrict__ x,       // [ntok]
    const int*   __restrict__ weight,  // [V, D] int4 values stored as int32
    const float* __restrict__ scale,   // [V, NG]
    const int*   __restrict__ zp,      // [V, NG]
    float*       __restrict__ out,     // [ntok, D]
    int ntok)
{
    const int tok0 = blockIdx.x * TOKS_PER_BLOCK;
    const int t    = threadIdx.x;        // 0..255
    const int d0   = t << 2;             // 0,4,...,1020
    const int g    = d0 >> 5;            // group of 32

    if (tok0 + TOKS_PER_BLOCK <= ntok) {
        // fast path: all 4 tokens valid
        int v[TOKS_PER_BLOCK];
#pragma unroll
        for (int i = 0; i < TOKS_PER_BLOCK; ++i)
            v[i] = x[tok0 + i];

        i32x4 w4[TOKS_PER_BLOCK];
        float s [TOKS_PER_BLOCK];
        float z [TOKS_PER_BLOCK];
#pragma unroll
        for (int i = 0; i < TOKS_PER_BLOCK; ++i) {
            const size_t rowW = (size_t)v[i] * EMB_D;
            const size_t rowG = (size_t)v[i] * EMB_NG;
            w4[i] = *reinterpret_cast<const i32x4*>(&weight[rowW + d0]);
            s[i]  = scale[rowG + g];
            z[i]  = (float)zp[rowG + g];
        }
#pragma unroll
        for (int i = 0; i < TOKS_PER_BLOCK; ++i) {
            f32x4 o;
            o.x = ((float)w4[i].x - z[i]) * s[i];
            o.y = ((float)w4[i].y - z[i]) * s[i];
            o.z = ((float)w4[i].z - z[i]) * s[i];
            o.w = ((float)w4[i].w - z[i]) * s[i];
            __builtin_nontemporal_store(
                o, reinterpret_cast<f32x4*>(&out[(size_t)(tok0 + i) * EMB_D + d0]));
        }
    } else {
        // tail path
        for (int i = 0; i < TOKS_PER_BLOCK; ++i) {
            const int tok = tok0 + i;
            if (tok >= ntok) break;
            const int vv = x[tok];
            const size_t rowW = (size_t)vv * EMB_D;
            const size_t rowG = (size_t)vv * EMB_NG;
            const float ss = scale[rowG + g];
            const float zz = (float)zp[rowG + g];
            const i32x4 w4 = *reinterpret_cast<const i32x4*>(&weight[rowW + d0]);
            f32x4 o;
            o.x = ((float)w4.x - zz) * ss;
            o.y = ((float)w4.y - zz) * ss;
            o.z = ((float)w4.z - zz) * ss;
            o.w = ((float)w4.w - zz) * ss;
            __builtin_nontemporal_store(
                o, reinterpret_cast<f32x4*>(&out[(size_t)tok * EMB_D + d0]));
        }
    }
}

extern "C" void kernel_launch(void* const* d_in, const int* in_sizes, int n_in,
                              void* d_out, int out_size, void* d_ws, size_t ws_size,
                              hipStream_t stream) {
    const int*   x      = (const int*)d_in[0];
    const int*   weight = (const int*)d_in[1];
    const float* scale  = (const float*)d_in[2];
    const int*   zp     = (const int*)d_in[3];
    float*       out    = (float*)d_out;

    const int ntok = in_sizes[0];        // 32 * 2048 = 65536

    const int nblocks = (ntok + TOKS_PER_BLOCK - 1) / TOKS_PER_BLOCK;
    int4_embed_dq_kernel<<<dim3(nblocks), dim3(256), 0, stream>>>(
        x, weight, scale, zp, out, ntok);
}